// Round 1
// baseline (614.362 us; speedup 1.0000x reference)
//
#include <hip/hip_runtime.h>
#include <math.h>

typedef __attribute__((ext_vector_type(8))) short  bf16x8;
typedef __attribute__((ext_vector_type(4))) float  f32x4;
typedef __attribute__((ext_vector_type(8))) unsigned short u16x8;

#define HID 128
#define BM  64

__device__ __forceinline__ unsigned short f2bf(float f) {
    union { float f; unsigned u; } v; v.f = f;
    unsigned u = v.u;
    return (unsigned short)((u + 0x7fffu + ((u >> 16) & 1u)) >> 16);
}
__device__ __forceinline__ float bf2f(unsigned short h) {
    union { unsigned u; float f; } v; v.u = ((unsigned)h) << 16;
    return v.f;
}
__device__ __forceinline__ float geluf(float x) {
    return 0.5f * x * (1.0f + erff(x * 0.70710678118654752440f));
}

// ---------------- weight prep: f32 [K][N] -> bf16 [N][K] ----------------
__global__ void prep_weights(const float* __restrict__ W11, const float* __restrict__ W12,
                             const float* __restrict__ W13,
                             unsigned short* __restrict__ w11t, unsigned short* __restrict__ w12t,
                             unsigned short* __restrict__ w13t) {
    int idx = blockIdx.x * 256 + threadIdx.x;
    if (idx < 512 * 128) {
        int k = idx >> 7, n = idx & 127;
        w11t[n * 512 + k] = f2bf(W11[idx]);
    } else if (idx < 512 * 128 + 128 * 128) {
        int j = idx - 512 * 128;
        int k = j >> 7, n = j & 127;
        w12t[n * 128 + k] = f2bf(W12[j]);
    } else if (idx < 512 * 128 + 2 * 128 * 128) {
        int j = idx - (512 * 128 + 128 * 128);
        int k = j >> 7, n = j & 127;
        w13t[n * 128 + k] = f2bf(W13[j]);
    }
}

// ---------------- fused MLP + residual + BN partials ----------------
// block = 256 threads (4 waves); tile = 64 edges x full 128 hidden.
// LDS row layout (per edge, 1024B): [hV[src] | hE | hV[dst] | vff] bf16, XOR-swizzled
// in 16B chunks: stored chunk = (c & ~7) | ((c ^ row) & 7).
// After GEMM1, h1 overwrites the vff region (+768B), h2 overwrites hV[dst] (+512B).
template <int XBF16>
__global__ __launch_bounds__(256, 2) void edge_mlp_kernel(
    const float* __restrict__ hV, const float* __restrict__ hE,
    const int* __restrict__ eidx, const float* __restrict__ vff,
    const unsigned short* __restrict__ w11t, const unsigned short* __restrict__ w12t,
    const unsigned short* __restrict__ w13t,
    const float* __restrict__ b11, const float* __restrict__ b12, const float* __restrict__ b13,
    float* __restrict__ psum, float* __restrict__ psumsq,
    float* __restrict__ xf32, unsigned short* __restrict__ xbf16,
    int E)
{
    __shared__ __align__(16) char lds[64 * 1024];
    const int tid  = threadIdx.x;
    const int lane = tid & 63;
    const int wid  = tid >> 6;
    const int lr   = lane & 15;
    const int lh   = lane >> 4;
    const int e0   = blockIdx.x * BM;

    // int64-vs-int32 edge_idx detection (int64 little-endian: odd 32b words are 0)
    const bool idx64 = ((eidx[1] | eidx[3] | eidx[5] | eidx[7]) == 0);

    // ---- stage h_EV tile: each wave loads one full 512-f32 row per iter ----
    const int cs  = lane;       // source 16B-chunk (8 f32 = 8 bf16 out)
    const int seg = cs >> 4;
    const int cin = cs & 15;
    for (int it = 0; it < 16; ++it) {
        int r = it * 4 + wid;
        int e = e0 + r;
        const float* sp;
        if (seg == 0) {
            int s = idx64 ? eidx[2 * e] : eidx[e];
            sp = hV + (size_t)s * HID + cin * 8;
        } else if (seg == 1) {
            sp = hE + (size_t)e * HID + cin * 8;
        } else if (seg == 2) {
            int d = idx64 ? eidx[2 * (E + e)] : eidx[E + e];
            sp = hV + (size_t)d * HID + cin * 8;
        } else {
            sp = vff + (size_t)e * HID + cin * 8;
        }
        f32x4 a = *(const f32x4*)sp;
        f32x4 b = *(const f32x4*)(sp + 4);
        u16x8 p;
        p[0] = f2bf(a[0]); p[1] = f2bf(a[1]); p[2] = f2bf(a[2]); p[3] = f2bf(a[3]);
        p[4] = f2bf(b[0]); p[5] = f2bf(b[1]); p[6] = f2bf(b[2]); p[7] = f2bf(b[3]);
        int cd = (cs & 56) | ((cs ^ r) & 7);
        *(u16x8*)(lds + r * 1024 + cd * 16) = p;
    }
    __syncthreads();

    const int n0 = (wid * 2) * 16 + lr;   // this wave's two output columns
    const int n1 = n0 + 16;

    f32x4 acc[2][4];
#pragma unroll
    for (int j = 0; j < 2; ++j)
#pragma unroll
        for (int m = 0; m < 4; ++m) acc[j][m] = (f32x4){0.f, 0.f, 0.f, 0.f};

    // ---- GEMM1: [64x512] @ [512x128] ----
    for (int kt = 0; kt < 16; ++kt) {
        bf16x8 b0 = *(const bf16x8*)(w11t + n0 * 512 + kt * 32 + lh * 8);
        bf16x8 b1 = *(const bf16x8*)(w11t + n1 * 512 + kt * 32 + lh * 8);
        int c = kt * 4 + lh;
#pragma unroll
        for (int m = 0; m < 4; ++m) {
            int row = m * 16 + lr;
            int cd  = (c & 56) | ((c ^ row) & 7);
            bf16x8 a = *(const bf16x8*)(lds + row * 1024 + cd * 16);
            acc[0][m] = __builtin_amdgcn_mfma_f32_16x16x32_bf16(a, b0, acc[0][m], 0, 0, 0);
            acc[1][m] = __builtin_amdgcn_mfma_f32_16x16x32_bf16(a, b1, acc[1][m], 0, 0, 0);
        }
    }
    __syncthreads();   // everyone done reading vff region before h1 overwrites it

    // ---- bias + GELU -> h1 into +768 region ----
    {
        float bv0 = b11[n0], bv1 = b11[n1];
#pragma unroll
        for (int m = 0; m < 4; ++m)
#pragma unroll
            for (int i = 0; i < 4; ++i) {
                int row = m * 16 + lh * 4 + i;
                float v0 = geluf(acc[0][m][i] + bv0);
                float v1 = geluf(acc[1][m][i] + bv1);
                int ch0 = n0 >> 3, ch1 = n1 >> 3;
                int s0 = (ch0 & 8) | ((ch0 ^ row) & 7);
                int s1 = (ch1 & 8) | ((ch1 ^ row) & 7);
                *(unsigned short*)(lds + row * 1024 + 768 + s0 * 16 + (n0 & 7) * 2) = f2bf(v0);
                *(unsigned short*)(lds + row * 1024 + 768 + s1 * 16 + (n1 & 7) * 2) = f2bf(v1);
            }
    }
    __syncthreads();

    // ---- GEMM2: [64x128] @ [128x128] ----
#pragma unroll
    for (int j = 0; j < 2; ++j)
#pragma unroll
        for (int m = 0; m < 4; ++m) acc[j][m] = (f32x4){0.f, 0.f, 0.f, 0.f};
    for (int kt = 0; kt < 4; ++kt) {
        bf16x8 b0 = *(const bf16x8*)(w12t + n0 * 128 + kt * 32 + lh * 8);
        bf16x8 b1 = *(const bf16x8*)(w12t + n1 * 128 + kt * 32 + lh * 8);
        int c = kt * 4 + lh;
#pragma unroll
        for (int m = 0; m < 4; ++m) {
            int row = m * 16 + lr;
            int s   = (c & 8) | ((c ^ row) & 7);
            bf16x8 a = *(const bf16x8*)(lds + row * 1024 + 768 + s * 16);
            acc[0][m] = __builtin_amdgcn_mfma_f32_16x16x32_bf16(a, b0, acc[0][m], 0, 0, 0);
            acc[1][m] = __builtin_amdgcn_mfma_f32_16x16x32_bf16(a, b1, acc[1][m], 0, 0, 0);
        }
    }
    // h2 region (+512) is disjoint from h1 region (+768): no barrier needed before write
    {
        float bv0 = b12[n0], bv1 = b12[n1];
#pragma unroll
        for (int m = 0; m < 4; ++m)
#pragma unroll
            for (int i = 0; i < 4; ++i) {
                int row = m * 16 + lh * 4 + i;
                float v0 = geluf(acc[0][m][i] + bv0);
                float v1 = geluf(acc[1][m][i] + bv1);
                int ch0 = n0 >> 3, ch1 = n1 >> 3;
                int s0 = (ch0 & 8) | ((ch0 ^ row) & 7);
                int s1 = (ch1 & 8) | ((ch1 ^ row) & 7);
                *(unsigned short*)(lds + row * 1024 + 512 + s0 * 16 + (n0 & 7) * 2) = f2bf(v0);
                *(unsigned short*)(lds + row * 1024 + 512 + s1 * 16 + (n1 & 7) * 2) = f2bf(v1);
            }
    }
    __syncthreads();

    // ---- GEMM3: [64x128] @ [128x128] ----
#pragma unroll
    for (int j = 0; j < 2; ++j)
#pragma unroll
        for (int m = 0; m < 4; ++m) acc[j][m] = (f32x4){0.f, 0.f, 0.f, 0.f};
    for (int kt = 0; kt < 4; ++kt) {
        bf16x8 b0 = *(const bf16x8*)(w13t + n0 * 128 + kt * 32 + lh * 8);
        bf16x8 b1 = *(const bf16x8*)(w13t + n1 * 128 + kt * 32 + lh * 8);
        int c = kt * 4 + lh;
#pragma unroll
        for (int m = 0; m < 4; ++m) {
            int row = m * 16 + lr;
            int s   = (c & 8) | ((c ^ row) & 7);
            bf16x8 a = *(const bf16x8*)(lds + row * 1024 + 512 + s * 16);
            acc[0][m] = __builtin_amdgcn_mfma_f32_16x16x32_bf16(a, b0, acc[0][m], 0, 0, 0);
            acc[1][m] = __builtin_amdgcn_mfma_f32_16x16x32_bf16(a, b1, acc[1][m], 0, 0, 0);
        }
    }

    // ---- epilogue: +b13, +h_E residual, write x, BN partial sums ----
    {
        float bv0 = b13[n0], bv1 = b13[n1];
        float s0 = 0.f, q0 = 0.f, s1 = 0.f, q1 = 0.f;
#pragma unroll
        for (int m = 0; m < 4; ++m)
#pragma unroll
            for (int i = 0; i < 4; ++i) {
                int row = m * 16 + lh * 4 + i;
                size_t e = (size_t)(e0 + row);
                int c0 = 16 + (n0 >> 3);
                int c1 = 16 + (n1 >> 3);
                int d0 = (c0 & 56) | ((c0 ^ row) & 7);
                int d1 = (c1 & 56) | ((c1 ^ row) & 7);
                float he0 = bf2f(*(unsigned short*)(lds + row * 1024 + d0 * 16 + (n0 & 7) * 2));
                float he1 = bf2f(*(unsigned short*)(lds + row * 1024 + d1 * 16 + (n1 & 7) * 2));
                float x0 = acc[0][m][i] + bv0 + he0;
                float x1 = acc[1][m][i] + bv1 + he1;
                s0 += x0; q0 += x0 * x0;
                s1 += x1; q1 += x1 * x1;
                if (XBF16) {
                    xbf16[e * HID + n0] = f2bf(x0);
                    xbf16[e * HID + n1] = f2bf(x1);
                } else {
                    xf32[e * HID + n0] = x0;
                    xf32[e * HID + n1] = x1;
                }
            }
        s0 += __shfl_xor(s0, 16); s0 += __shfl_xor(s0, 32);
        q0 += __shfl_xor(q0, 16); q0 += __shfl_xor(q0, 32);
        s1 += __shfl_xor(s1, 16); s1 += __shfl_xor(s1, 32);
        q1 += __shfl_xor(q1, 16); q1 += __shfl_xor(q1, 32);
        if (lane < 16) {
            size_t base = (size_t)blockIdx.x * HID;
            psum[base + n0]   = s0;
            psum[base + n1]   = s1;
            psumsq[base + n0] = q0;
            psumsq[base + n1] = q1;
        }
    }
}

// ---------------- BN stats: reduce per-block partials -> scale/shift ----------------
__global__ void bn_stats_kernel(const float* __restrict__ psum, const float* __restrict__ psumsq,
                                const float* __restrict__ gamma, const float* __restrict__ beta,
                                float* __restrict__ params, int nblk, float invE) {
    int c = blockIdx.x;   // channel 0..127
    float s = 0.f, q = 0.f;
    for (int i = threadIdx.x; i < nblk; i += 256) {
        s += psum[(size_t)i * 128 + c];
        q += psumsq[(size_t)i * 128 + c];
    }
#pragma unroll
    for (int o = 1; o < 64; o <<= 1) { s += __shfl_xor(s, o); q += __shfl_xor(q, o); }
    __shared__ float as[4], aq[4];
    int w = threadIdx.x >> 6;
    if ((threadIdx.x & 63) == 0) { as[w] = s; aq[w] = q; }
    __syncthreads();
    if (threadIdx.x == 0) {
        float S  = as[0] + as[1] + as[2] + as[3];
        float Q  = aq[0] + aq[1] + aq[2] + aq[3];
        float mean = S * invE;
        float var  = Q * invE - mean * mean;
        float sc   = gamma[c] * rsqrtf(var + 1e-5f);
        params[c]       = sc;
        params[128 + c] = beta[c] - mean * sc;
    }
}

// ---------------- BN apply ----------------
__global__ void bn_apply_bf16(const unsigned short* __restrict__ x, float* __restrict__ out,
                              const float* __restrict__ params, int total8) {
    __shared__ float sc[128], sh[128];
    if (threadIdx.x < 128) { sc[threadIdx.x] = params[threadIdx.x]; sh[threadIdx.x] = params[128 + threadIdx.x]; }
    __syncthreads();
    int stride = gridDim.x * blockDim.x;
    for (int i = blockIdx.x * blockDim.x + threadIdx.x; i < total8; i += stride) {
        size_t base = (size_t)i * 8;
        u16x8 v = *(const u16x8*)(x + base);
        int c0 = (int)(base & 127);
        f32x4 o0, o1;
#pragma unroll
        for (int e = 0; e < 4; ++e) o0[e] = bf2f(v[e]) * sc[c0 + e] + sh[c0 + e];
#pragma unroll
        for (int e = 0; e < 4; ++e) o1[e] = bf2f(v[4 + e]) * sc[c0 + 4 + e] + sh[c0 + 4 + e];
        *(f32x4*)(out + base)     = o0;
        *(f32x4*)(out + base + 4) = o1;
    }
}

__global__ void bn_apply_f32(float* __restrict__ x, const float* __restrict__ params, int total4) {
    __shared__ float sc[128], sh[128];
    if (threadIdx.x < 128) { sc[threadIdx.x] = params[threadIdx.x]; sh[threadIdx.x] = params[128 + threadIdx.x]; }
    __syncthreads();
    int stride = gridDim.x * blockDim.x;
    for (int i = blockIdx.x * blockDim.x + threadIdx.x; i < total4; i += stride) {
        size_t base = (size_t)i * 4;
        f32x4 v = *(f32x4*)(x + base);
        int c0 = (int)(base & 127);
#pragma unroll
        for (int e = 0; e < 4; ++e) v[e] = v[e] * sc[c0 + e] + sh[c0 + e];
        *(f32x4*)(x + base) = v;
    }
}

extern "C" void kernel_launch(void* const* d_in, const int* in_sizes, int n_in,
                              void* d_out, int out_size, void* d_ws, size_t ws_size,
                              hipStream_t stream) {
    const float* hV    = (const float*)d_in[0];
    const float* hE    = (const float*)d_in[1];
    const int*   eidx  = (const int*)d_in[2];
    const float* vff   = (const float*)d_in[4];
    const float* W11   = (const float*)d_in[5];
    const float* b11   = (const float*)d_in[6];
    const float* W12   = (const float*)d_in[7];
    const float* b12   = (const float*)d_in[8];
    const float* W13   = (const float*)d_in[9];
    const float* b13   = (const float*)d_in[10];
    const float* gamma = (const float*)d_in[11];
    const float* beta  = (const float*)d_in[12];

    const int E    = in_sizes[1] / HID;
    const int nblk = E / BM;

    float* psum   = (float*)d_ws;
    float* psumsq = psum + (size_t)nblk * HID;
    float* params = psumsq + (size_t)nblk * HID;
    unsigned short* w11t = (unsigned short*)(params + 256);
    unsigned short* w12t = w11t + 512 * 128;
    unsigned short* w13t = w12t + 128 * 128;
    size_t xoff = ((size_t)((char*)(w13t + 128 * 128) - (char*)d_ws) + 15) & ~(size_t)15;
    unsigned short* xbf = (unsigned short*)((char*)d_ws + xoff);
    const bool useBf = ws_size >= xoff + (size_t)E * HID * 2;

    prep_weights<<<384, 256, 0, stream>>>(W11, W12, W13, w11t, w12t, w13t);

    if (useBf)
        edge_mlp_kernel<1><<<nblk, 256, 0, stream>>>(hV, hE, eidx, vff, w11t, w12t, w13t,
                                                     b11, b12, b13, psum, psumsq,
                                                     (float*)d_out, xbf, E);
    else
        edge_mlp_kernel<0><<<nblk, 256, 0, stream>>>(hV, hE, eidx, vff, w11t, w12t, w13t,
                                                     b11, b12, b13, psum, psumsq,
                                                     (float*)d_out, xbf, E);

    bn_stats_kernel<<<128, 256, 0, stream>>>(psum, psumsq, gamma, beta, params, nblk,
                                             1.0f / (float)E);

    if (useBf)
        bn_apply_bf16<<<2048, 256, 0, stream>>>(xbf, (float*)d_out, params, E * HID / 8);
    else
        bn_apply_f32<<<2048, 256, 0, stream>>>((float*)d_out, params, E * HID / 4);
}